// Round 3
// baseline (748.262 us; speedup 1.0000x reference)
//
#include <hip/hip_runtime.h>
#include <hip/hip_bf16.h>

typedef __bf16 bf16;
typedef __bf16 bf16x8 __attribute__((ext_vector_type(8)));
typedef float  floatx4 __attribute__((ext_vector_type(4)));

#define AS1 __attribute__((address_space(1)))
#define AS3 __attribute__((address_space(3)))

#define B_    2
#define S_    2048
#define D_    2048
#define H_    16
#define KVH_  8
#define DH_   128
#define M_    4096      // B_*S_
#define NQKV_ 4096      // D_ + 2*KVH_*DH_

// ---------------------------------------------------------------- cast fp32 -> bf16
__global__ __launch_bounds__(256) void cast_kernel(const float* __restrict__ in,
                                                   bf16* __restrict__ out, int n) {
    int i = (blockIdx.x * blockDim.x + threadIdx.x) * 4;
    if (i < n) {
        float4 v = *(const float4*)(in + i);
        union { bf16 h[4]; double d; } u;
        u.h[0] = (bf16)v.x; u.h[1] = (bf16)v.y; u.h[2] = (bf16)v.z; u.h[3] = (bf16)v.w;
        *(double*)(out + i) = u.d;
    }
}

// ---------------------------------------------------------------- RoPE tables [S][64]
__global__ __launch_bounds__(256) void rope_table(float* __restrict__ cost,
                                                  float* __restrict__ sint) {
    int i = blockIdx.x * blockDim.x + threadIdx.x;   // S_*64 threads
    int t = i >> 6, fi = i & 63;
    float inv = expf(-9.210340371976184f * (float)fi * (1.0f / 64.0f)); // 10000^(-fi/64)
    float ang = (float)t * inv;
    cost[i] = cosf(ang);
    sint[i] = sinf(ang);
}

// ---------------------------------------------------------------- GEMM: C[M,N] = A[M,K] * B[N,K]^T   (bf16 in, fp32 acc, CT out)
#define BM 128
#define BN 128
#define BK 64
template <typename CT>
__global__ __launch_bounds__(256) void gemm_bt(const bf16* __restrict__ A,
                                               const bf16* __restrict__ Bw,
                                               CT* __restrict__ C,
                                               int M, int N, int K) {
    __shared__ __align__(16) bf16 Als[BM * BK];
    __shared__ __align__(16) bf16 Bls[BN * BK];
    int tid  = threadIdx.x;
    int wave = tid >> 6, lane = tid & 63;
    int quad = lane >> 4, l16 = lane & 15;
    int wm = (wave >> 1) << 6;   // 0 / 64
    int wn = (wave & 1) << 6;

    long bm0 = (long)blockIdx.y * BM;
    long bn0 = (long)blockIdx.x * BN;
    const bf16* Ab = A  + bm0 * K;
    const bf16* Bb = Bw + bn0 * K;

    // staging: wave w covers rows [w*32, w*32+32); global col-group XOR-swizzled
    // by row&7 so the contiguous LDS destination (base+lane*16) ends up swizzled.
    int srow = wave * 32 + (lane >> 3);
    int scol = ((lane & 7) ^ (lane >> 3)) << 3;
    int sdst = (wave * 32 + (lane >> 3)) * BK + ((lane & 7) << 3); // == wave*2048 + lane*8 elems

    floatx4 acc[4][4] = {};

    for (int k0 = 0; k0 < K; k0 += BK) {
        #pragma unroll
        for (int i = 0; i < 4; ++i) {
            const bf16* ga = Ab + (long)(srow + i * 8) * K + k0 + scol;
            const bf16* gb = Bb + (long)(srow + i * 8) * K + k0 + scol;
            __builtin_amdgcn_global_load_lds((AS1 const unsigned int*)ga,
                                             (AS3 unsigned int*)(Als + sdst + i * 512), 16, 0, 0);
            __builtin_amdgcn_global_load_lds((AS1 const unsigned int*)gb,
                                             (AS3 unsigned int*)(Bls + sdst + i * 512), 16, 0, 0);
        }
        __syncthreads();
        #pragma unroll
        for (int ks = 0; ks < 2; ++ks) {
            bf16x8 af[4], bfr[4];
            #pragma unroll
            for (int t = 0; t < 4; ++t) {
                int row = wm + t * 16 + l16;
                int g = (ks * 4 + quad) ^ (row & 7);
                af[t] = *(const bf16x8*)(Als + row * BK + (g << 3));
            }
            #pragma unroll
            for (int t = 0; t < 4; ++t) {
                int row = wn + t * 16 + l16;
                int g = (ks * 4 + quad) ^ (row & 7);
                bfr[t] = *(const bf16x8*)(Bls + row * BK + (g << 3));
            }
            #pragma unroll
            for (int mt = 0; mt < 4; ++mt)
                #pragma unroll
                for (int nt = 0; nt < 4; ++nt)
                    acc[mt][nt] = __builtin_amdgcn_mfma_f32_16x16x32_bf16(af[mt], bfr[nt], acc[mt][nt], 0, 0, 0);
        }
        __syncthreads();
    }
    // C/D layout: col = lane&15, row = quad*4 + reg
    #pragma unroll
    for (int mt = 0; mt < 4; ++mt) {
        #pragma unroll
        for (int nt = 0; nt < 4; ++nt) {
            long row = bm0 + wm + mt * 16 + quad * 4;
            long col = bn0 + wn + nt * 16 + l16;
            #pragma unroll
            for (int r = 0; r < 4; ++r)
                C[(row + r) * N + col] = (CT)acc[mt][nt][r];
        }
    }
}

// ---------------------------------------------------------------- canon_b + RMSNorm + RoPE
// QKV [M_,4096] bf16 (q|k|v along N). Writes qf[B][H][S][128], kf[B][KVH][S][128], vf[B][KVH][S][128].
__global__ __launch_bounds__(512) void canon_kernel(const bf16* __restrict__ QKV,
                                                    const float* __restrict__ wq,
                                                    const float* __restrict__ wk,
                                                    const float* __restrict__ wv,
                                                    const float* __restrict__ qnw,
                                                    const float* __restrict__ knw,
                                                    const float* __restrict__ cost,
                                                    const float* __restrict__ sint,
                                                    bf16* __restrict__ qf,
                                                    bf16* __restrict__ kf,
                                                    bf16* __restrict__ vf) {
    int row = blockIdx.x;
    int b = row >> 11, t = row & 2047;
    int tid = threadIdx.x;
    int c0 = tid << 3;                         // 8 channels per thread
    __shared__ float vals[4096];
    __shared__ float rrms[24];

    const float* wrow; int cw;
    if (c0 < 2048)      { wrow = wq; cw = c0; }
    else if (c0 < 3072) { wrow = wk; cw = c0 - 2048; }
    else                { wrow = wv; cw = c0 - 3072; }

    float4 w4[8];
    #pragma unroll
    for (int j = 0; j < 8; ++j) w4[j] = *(const float4*)(wrow + (cw + j) * 4);

    union U8 { float4 v; bf16 h[8]; };
    float acc[8];
    {
        U8 u; u.v = *(const float4*)(QKV + (size_t)row * 4096 + c0);
        #pragma unroll
        for (int j = 0; j < 8; ++j) acc[j] = (float)u.h[j];   // residual x[t]
    }
    #pragma unroll
    for (int kk = 0; kk < 4; ++kk) {
        int tt = t - kk;
        if (tt >= 0) {
            U8 u; u.v = *(const float4*)(QKV + ((size_t)((b << 11) + tt)) * 4096 + c0);
            #pragma unroll
            for (int j = 0; j < 8; ++j) acc[j] += (&w4[j].x)[kk] * (float)u.h[j];
        }
    }
    #pragma unroll
    for (int j = 0; j < 8; ++j) vals[c0 + j] = acc[j];
    __syncthreads();

    if (tid < 384) {     // 24 heads (16 q + 8 k) * 16 threads
        int hh = tid >> 4, sub = tid & 15;
        const float* vp = vals + hh * 128 + sub * 8;
        float ss = 0.f;
        #pragma unroll
        for (int j = 0; j < 8; ++j) ss += vp[j] * vp[j];
        ss += __shfl_xor(ss, 1); ss += __shfl_xor(ss, 2);
        ss += __shfl_xor(ss, 4); ss += __shfl_xor(ss, 8);
        if (sub == 0) rrms[hh] = rsqrtf(ss * (1.0f / 128.0f) + 1e-6f);
    }
    __syncthreads();

    if (c0 < 3072) {     // q or k: norm + rope
        int ch   = (c0 < 2048) ? c0 : c0 - 2048;
        int head = ch >> 7;
        int j0   = ch & 127;
        int hb   = c0 - j0;                       // head base in vals space
        const float* nw = (c0 < 2048) ? qnw : knw;
        float r1 = rrms[c0 >> 7];
        const float* ct = cost + t * 64;
        const float* st = sint + t * 64;
        __align__(16) bf16 outv[8];
        #pragma unroll
        for (int j = 0; j < 8; ++j) {
            int jj = j0 + j;
            float xn = vals[hb + jj] * r1 * nw[jj];
            int pj = (jj < 64) ? jj + 64 : jj - 64;
            float xp = vals[hb + pj] * r1 * nw[pj];
            float rot = (jj < 64) ? -xp : xp;
            int fi = jj & 63;
            outv[j] = (bf16)(xn * ct[fi] + rot * st[fi]);
        }
        bf16* dst = (c0 < 2048)
            ? qf + ((((size_t)b * H_  + head) * S_ + t) << 7) + j0
            : kf + ((((size_t)b * KVH_ + head) * S_ + t) << 7) + j0;
        *(float4*)dst = *(float4*)outv;
    } else {             // v: conv only
        int ch = c0 - 3072;
        int head = ch >> 7, j0 = ch & 127;
        __align__(16) bf16 outv[8];
        #pragma unroll
        for (int j = 0; j < 8; ++j) outv[j] = (bf16)acc[j];
        bf16* dst = vf + ((((size_t)b * KVH_ + head) * S_ + t) << 7) + j0;
        *(float4*)dst = *(float4*)outv;
    }
}

// ---------------------------------------------------------------- V transpose: [bk][S][128] -> [bk][128][S]
__global__ __launch_bounds__(256) void transpose_v(const bf16* __restrict__ vf,
                                                   bf16* __restrict__ vfT) {
    __shared__ __align__(16) bf16 tile[64][72];
    int bk = blockIdx.z;
    int t0 = blockIdx.x * 64;
    int d0 = blockIdx.y * 64;
    int tid = threadIdx.x;
    const bf16* src = vf + ((size_t)bk * S_ << 7);
    {
        int r = tid >> 3, cs = (tid & 7) << 3;
        #pragma unroll
        for (int p = 0; p < 2; ++p)
            *(float4*)(&tile[r + p * 32][cs]) =
                *(const float4*)(src + (size_t)(t0 + r + p * 32) * 128 + d0 + cs);
    }
    __syncthreads();
    {
        int dr = tid >> 3, ts = (tid & 7) << 3;
        #pragma unroll
        for (int p = 0; p < 2; ++p) {
            __align__(16) bf16 outv[8];
            #pragma unroll
            for (int j = 0; j < 8; ++j) outv[j] = tile[ts + j][dr + p * 32];
            *(float4*)(vfT + ((size_t)bk * 128 + d0 + dr + p * 32) * S_ + t0 + ts) = *(float4*)outv;
        }
    }
}

// ---------------------------------------------------------------- flash attention (causal, GQA groups=2)
// qf[B][H][S][128], kf[B][KVH][S][128], vfT[B][KVH][128][S] -> attn[B][S][H*128]
__global__ __launch_bounds__(256) void flash_attn(const bf16* __restrict__ qf,
                                                  const bf16* __restrict__ kf,
                                                  const bf16* __restrict__ vfT,
                                                  bf16* __restrict__ attn) {
    __shared__ __align__(16) bf16 Kls[64][136];    // [key][d], +8 pad
    __shared__ __align__(16) bf16 Vls[128][72];    // [d][key], +8 pad
    __shared__ __align__(16) bf16 Pls[4][16][72];  // per-wave P, +8 pad
    int qt = gridDim.x - 1 - blockIdx.x;           // longest blocks first
    int h = blockIdx.y, b = blockIdx.z;
    int kvh = h >> 1;
    int tid = threadIdx.x, wave = tid >> 6, lane = tid & 63;
    int quad = lane >> 4, l16 = lane & 15;
    int qbase = qt << 6;
    int qrow0 = qbase + (wave << 4);               // wave's 16 q rows

    const bf16* kbase = kf  + (((size_t)b * KVH_ + kvh) * S_ << 7);
    const bf16* vbase = vfT + (((size_t)b * KVH_ + kvh) << 7) * S_;

    bf16x8 aq[4];   // Q A-frags over d (4 * 32)
    {
        const bf16* qr = qf + ((((size_t)b * H_ + h) * S_ + qrow0 + l16) << 7) + (quad << 3);
        #pragma unroll
        for (int ks = 0; ks < 4; ++ks) aq[ks] = *(const bf16x8*)(qr + ks * 32);
    }
    floatx4 o[8] = {};
    float m_i[4] = {-1e30f, -1e30f, -1e30f, -1e30f};
    float l_i[4] = {0.f, 0.f, 0.f, 0.f};
    const float scale = 0.08838834764831845f;      // 1/sqrt(128)

    int ktiles = qt + 1;
    for (int kt = 0; kt < ktiles; ++kt) {
        int kb = kt << 6;
        {   // stage K [64][128] and V^T [128][64]
            int r = tid >> 4, cs = (tid & 15) << 3;
            #pragma unroll
            for (int i = 0; i < 4; ++i)
                *(float4*)(&Kls[r + i * 16][cs]) =
                    *(const float4*)(kbase + ((size_t)(kb + r + i * 16) << 7) + cs);
            int d = tid >> 3, ts = (tid & 7) << 3;
            #pragma unroll
            for (int i = 0; i < 4; ++i)
                *(float4*)(&Vls[d + i * 32][ts]) =
                    *(const float4*)(vbase + (size_t)(d + i * 32) * S_ + kb + ts);
        }
        __syncthreads();
        // S = Q K^T
        floatx4 sc[4] = {};
        #pragma unroll
        for (int ks = 0; ks < 4; ++ks) {
            #pragma unroll
            for (int nt = 0; nt < 4; ++nt) {
                bf16x8 kb8 = *(const bf16x8*)(&Kls[nt * 16 + l16][ks * 32 + (quad << 3)]);
                sc[nt] = __builtin_amdgcn_mfma_f32_16x16x32_bf16(aq[ks], kb8, sc[nt], 0, 0, 0);
            }
        }
        // scale + causal mask
        int qr0 = qrow0 + (quad << 2);
        #pragma unroll
        for (int nt = 0; nt < 4; ++nt) {
            int key = kb + nt * 16 + l16;
            #pragma unroll
            for (int r = 0; r < 4; ++r) {
                float s = sc[nt][r] * scale;
                sc[nt][r] = (key <= qr0 + r) ? s : -1e30f;
            }
        }
        // online softmax (per lane: 4 rows)
        #pragma unroll
        for (int r = 0; r < 4; ++r) {
            float mx = fmaxf(fmaxf(sc[0][r], sc[1][r]), fmaxf(sc[2][r], sc[3][r]));
            mx = fmaxf(mx, __shfl_xor(mx, 1)); mx = fmaxf(mx, __shfl_xor(mx, 2));
            mx = fmaxf(mx, __shfl_xor(mx, 4)); mx = fmaxf(mx, __shfl_xor(mx, 8));
            float mnew = fmaxf(m_i[r], mx);
            float alpha = expf(m_i[r] - mnew);
            m_i[r] = mnew;
            float sum = 0.f;
            #pragma unroll
            for (int nt = 0; nt < 4; ++nt) {
                float pv = expf(sc[nt][r] - mnew);
                sc[nt][r] = pv;
                sum += pv;
            }
            sum += __shfl_xor(sum, 1); sum += __shfl_xor(sum, 2);
            sum += __shfl_xor(sum, 4); sum += __shfl_xor(sum, 8);
            l_i[r] = l_i[r] * alpha + sum;
            #pragma unroll
            for (int dnt = 0; dnt < 8; ++dnt) o[dnt][r] *= alpha;
            #pragma unroll
            for (int nt = 0; nt < 4; ++nt)
                Pls[wave][(quad << 2) + r][nt * 16 + l16] = (bf16)sc[nt][r];
        }
        __syncthreads();
        // O += P V
        #pragma unroll
        for (int ks = 0; ks < 2; ++ks) {
            bf16x8 pa = *(const bf16x8*)(&Pls[wave][l16][ks * 32 + (quad << 3)]);
            #pragma unroll
            for (int dnt = 0; dnt < 8; ++dnt) {
                bf16x8 vb = *(const bf16x8*)(&Vls[dnt * 16 + l16][ks * 32 + (quad << 3)]);
                o[dnt] = __builtin_amdgcn_mfma_f32_16x16x32_bf16(pa, vb, o[dnt], 0, 0, 0);
            }
        }
        __syncthreads();
    }
    // epilogue: attn[b][q][h*128 + d] = o / l
    #pragma unroll
    for (int dnt = 0; dnt < 8; ++dnt) {
        #pragma unroll
        for (int r = 0; r < 4; ++r) {
            size_t row = (size_t)b * S_ + qrow0 + (quad << 2) + r;
            attn[row * D_ + h * DH_ + dnt * 16 + l16] = (bf16)(o[dnt][r] / l_i[r]);
        }
    }
}

// ---------------------------------------------------------------- launch
extern "C" void kernel_launch(void* const* d_in, const int* in_sizes, int n_in,
                              void* d_out, int out_size, void* d_ws, size_t ws_size,
                              hipStream_t stream) {
    // Inputs are float32 (per reference); output is float32.
    const float* hidden = (const float*)d_in[0];
    const float* Wq  = (const float*)d_in[1];
    const float* Wk  = (const float*)d_in[2];
    const float* Wv  = (const float*)d_in[3];
    const float* Wo  = (const float*)d_in[4];
    const float* cqw = (const float*)d_in[5];
    const float* ckw = (const float*)d_in[6];
    const float* cvw = (const float*)d_in[7];
    const float* qnw = (const float*)d_in[8];
    const float* knw = (const float*)d_in[9];

    char* p = (char*)d_ws;
    auto alloc = [&](size_t bytes) { char* r = p; p += (bytes + 255) & ~(size_t)255; return r; };
    bf16*  X    = (bf16*)alloc((size_t)M_ * D_ * 2);
    bf16*  Wcat = (bf16*)alloc((size_t)NQKV_ * D_ * 2);
    bf16*  Wob  = (bf16*)alloc((size_t)D_ * D_ * 2);
    bf16*  QKV  = (bf16*)alloc((size_t)M_ * NQKV_ * 2);
    bf16*  qfb  = (bf16*)alloc((size_t)B_ * H_ * S_ * DH_ * 2);
    bf16*  kfb  = (bf16*)alloc((size_t)B_ * KVH_ * S_ * DH_ * 2);
    bf16*  vfb  = (bf16*)alloc((size_t)B_ * KVH_ * S_ * DH_ * 2);
    bf16*  vfT  = (bf16*)alloc((size_t)B_ * KVH_ * S_ * DH_ * 2);
    float* cost = (float*)alloc((size_t)S_ * 64 * 4);
    float* sint = (float*)alloc((size_t)S_ * 64 * 4);
    bf16*  attnb = QKV;   // QKV is dead after canon_kernel; reuse as attention output

    cast_kernel<<<M_ * D_ / 4 / 256, 256, 0, stream>>>(hidden, X, M_ * D_);
    cast_kernel<<<D_ * D_ / 4 / 256, 256, 0, stream>>>(Wq, Wcat, D_ * D_);
    cast_kernel<<<1024 * 2048 / 4 / 256, 256, 0, stream>>>(Wk, Wcat + (size_t)2048 * 2048, 1024 * 2048);
    cast_kernel<<<1024 * 2048 / 4 / 256, 256, 0, stream>>>(Wv, Wcat + (size_t)3072 * 2048, 1024 * 2048);
    cast_kernel<<<D_ * D_ / 4 / 256, 256, 0, stream>>>(Wo, Wob, D_ * D_);
    rope_table<<<S_ * 64 / 256, 256, 0, stream>>>(cost, sint);

    gemm_bt<bf16><<<dim3(NQKV_ / BN, M_ / BM), 256, 0, stream>>>(X, Wcat, QKV, M_, NQKV_, D_);
    canon_kernel<<<M_, 512, 0, stream>>>(QKV, cqw, ckw, cvw, qnw, knw, cost, sint, qfb, kfb, vfb);
    transpose_v<<<dim3(S_ / 64, DH_ / 64, B_ * KVH_), 256, 0, stream>>>(vfb, vfT);
    flash_attn<<<dim3(S_ / 64, H_, B_), 256, 0, stream>>>(qfb, kfb, vfT, attnb);
    gemm_bt<float><<<dim3(D_ / BN, M_ / BM), 256, 0, stream>>>(attnb, Wob, (float*)d_out, M_, D_, D_);
}

// Round 4
// 678.618 us; speedup vs baseline: 1.1026x; 1.1026x over previous
//
#include <hip/hip_runtime.h>
#include <hip/hip_bf16.h>

typedef __bf16 bf16;
typedef __bf16 bf16x8 __attribute__((ext_vector_type(8)));
typedef float  floatx4 __attribute__((ext_vector_type(4)));

#define AS1 __attribute__((address_space(1)))
#define AS3 __attribute__((address_space(3)))

#define B_    2
#define S_    2048
#define D_    2048
#define H_    16
#define KVH_  8
#define DH_   128
#define M_    4096      // B_*S_
#define NQKV_ 4096      // D_ + 2*KVH_*DH_

// ---------------------------------------------------------------- cast fp32 -> bf16
__global__ __launch_bounds__(256) void cast_kernel(const float* __restrict__ in,
                                                   bf16* __restrict__ out, int n) {
    int i = (blockIdx.x * blockDim.x + threadIdx.x) * 4;
    if (i < n) {
        float4 v = *(const float4*)(in + i);
        union { bf16 h[4]; double d; } u;
        u.h[0] = (bf16)v.x; u.h[1] = (bf16)v.y; u.h[2] = (bf16)v.z; u.h[3] = (bf16)v.w;
        *(double*)(out + i) = u.d;
    }
}

// ---------------------------------------------------------------- RoPE tables [S][64]
__global__ __launch_bounds__(256) void rope_table(float* __restrict__ cost,
                                                  float* __restrict__ sint) {
    int i = blockIdx.x * blockDim.x + threadIdx.x;   // S_*64 threads
    int t = i >> 6, fi = i & 63;
    float inv = expf(-9.210340371976184f * (float)fi * (1.0f / 64.0f)); // 10000^(-fi/64)
    float ang = (float)t * inv;
    cost[i] = cosf(ang);
    sint[i] = sinf(ang);
}

// ---------------------------------------------------------------- GEMM: C[M,N] = A[M,K] * B[N,K]^T   (bf16 in, fp32 acc, CT out)
#define BM 128
#define BN 128
#define BK 64
template <typename CT>
__global__ __launch_bounds__(256) void gemm_bt(const bf16* __restrict__ A,
                                               const bf16* __restrict__ Bw,
                                               CT* __restrict__ C,
                                               int M, int N, int K) {
    __shared__ __align__(16) bf16 Als[BM * BK];
    __shared__ __align__(16) bf16 Bls[BN * BK];
    int tid  = threadIdx.x;
    int wave = tid >> 6, lane = tid & 63;
    int quad = lane >> 4, l16 = lane & 15;
    int wm = (wave >> 1) << 6;   // 0 / 64
    int wn = (wave & 1) << 6;

    long bm0 = (long)blockIdx.y * BM;
    long bn0 = (long)blockIdx.x * BN;
    const bf16* Ab = A  + bm0 * K;
    const bf16* Bb = Bw + bn0 * K;

    // staging: wave w covers rows [w*32, w*32+32); global col-group XOR-swizzled
    // by row&7 so the contiguous LDS destination (base+lane*16) ends up swizzled.
    int srow = wave * 32 + (lane >> 3);
    int scol = ((lane & 7) ^ (lane >> 3)) << 3;
    int sdst = (wave * 32 + (lane >> 3)) * BK + ((lane & 7) << 3); // == wave*2048 + lane*8 elems

    floatx4 acc[4][4] = {};

    for (int k0 = 0; k0 < K; k0 += BK) {
        #pragma unroll
        for (int i = 0; i < 4; ++i) {
            const bf16* ga = Ab + (long)(srow + i * 8) * K + k0 + scol;
            const bf16* gb = Bb + (long)(srow + i * 8) * K + k0 + scol;
            __builtin_amdgcn_global_load_lds((AS1 const unsigned int*)ga,
                                             (AS3 unsigned int*)(Als + sdst + i * 512), 16, 0, 0);
            __builtin_amdgcn_global_load_lds((AS1 const unsigned int*)gb,
                                             (AS3 unsigned int*)(Bls + sdst + i * 512), 16, 0, 0);
        }
        __syncthreads();
        #pragma unroll
        for (int ks = 0; ks < 2; ++ks) {
            bf16x8 af[4], bfr[4];
            #pragma unroll
            for (int t = 0; t < 4; ++t) {
                int row = wm + t * 16 + l16;
                int g = (ks * 4 + quad) ^ (row & 7);
                af[t] = *(const bf16x8*)(Als + row * BK + (g << 3));
            }
            #pragma unroll
            for (int t = 0; t < 4; ++t) {
                int row = wn + t * 16 + l16;
                int g = (ks * 4 + quad) ^ (row & 7);
                bfr[t] = *(const bf16x8*)(Bls + row * BK + (g << 3));
            }
            #pragma unroll
            for (int mt = 0; mt < 4; ++mt)
                #pragma unroll
                for (int nt = 0; nt < 4; ++nt)
                    acc[mt][nt] = __builtin_amdgcn_mfma_f32_16x16x32_bf16(af[mt], bfr[nt], acc[mt][nt], 0, 0, 0);
        }
        __syncthreads();
    }
    // C/D layout: col = lane&15, row = quad*4 + reg
    #pragma unroll
    for (int mt = 0; mt < 4; ++mt) {
        #pragma unroll
        for (int nt = 0; nt < 4; ++nt) {
            long row = bm0 + wm + mt * 16 + quad * 4;
            long col = bn0 + wn + nt * 16 + l16;
            #pragma unroll
            for (int r = 0; r < 4; ++r)
                C[(row + r) * N + col] = (CT)acc[mt][nt][r];
        }
    }
}

// ---------------------------------------------------------------- canon_b + RMSNorm + RoPE
__global__ __launch_bounds__(512) void canon_kernel(const bf16* __restrict__ QKV,
                                                    const float* __restrict__ wq,
                                                    const float* __restrict__ wk,
                                                    const float* __restrict__ wv,
                                                    const float* __restrict__ qnw,
                                                    const float* __restrict__ knw,
                                                    const float* __restrict__ cost,
                                                    const float* __restrict__ sint,
                                                    bf16* __restrict__ qf,
                                                    bf16* __restrict__ kf,
                                                    bf16* __restrict__ vf) {
    int row = blockIdx.x;
    int b = row >> 11, t = row & 2047;
    int tid = threadIdx.x;
    int c0 = tid << 3;                         // 8 channels per thread
    __shared__ float vals[4096];
    __shared__ float rrms[24];

    const float* wrow; int cw;
    if (c0 < 2048)      { wrow = wq; cw = c0; }
    else if (c0 < 3072) { wrow = wk; cw = c0 - 2048; }
    else                { wrow = wv; cw = c0 - 3072; }

    float4 w4[8];
    #pragma unroll
    for (int j = 0; j < 8; ++j) w4[j] = *(const float4*)(wrow + (cw + j) * 4);

    union U8 { float4 v; bf16 h[8]; };
    float acc[8];
    {
        U8 u; u.v = *(const float4*)(QKV + (size_t)row * 4096 + c0);
        #pragma unroll
        for (int j = 0; j < 8; ++j) acc[j] = (float)u.h[j];   // residual x[t]
    }
    #pragma unroll
    for (int kk = 0; kk < 4; ++kk) {
        int tt = t - kk;
        if (tt >= 0) {
            U8 u; u.v = *(const float4*)(QKV + ((size_t)((b << 11) + tt)) * 4096 + c0);
            #pragma unroll
            for (int j = 0; j < 8; ++j) acc[j] += (&w4[j].x)[kk] * (float)u.h[j];
        }
    }
    #pragma unroll
    for (int j = 0; j < 8; ++j) vals[c0 + j] = acc[j];
    __syncthreads();

    if (tid < 384) {     // 24 heads (16 q + 8 k) * 16 threads
        int hh = tid >> 4, sub = tid & 15;
        const float* vp = vals + hh * 128 + sub * 8;
        float ss = 0.f;
        #pragma unroll
        for (int j = 0; j < 8; ++j) ss += vp[j] * vp[j];
        ss += __shfl_xor(ss, 1); ss += __shfl_xor(ss, 2);
        ss += __shfl_xor(ss, 4); ss += __shfl_xor(ss, 8);
        if (sub == 0) rrms[hh] = rsqrtf(ss * (1.0f / 128.0f) + 1e-6f);
    }
    __syncthreads();

    if (c0 < 3072) {     // q or k: norm + rope
        int ch   = (c0 < 2048) ? c0 : c0 - 2048;
        int head = ch >> 7;
        int j0   = ch & 127;
        int hb   = c0 - j0;                       // head base in vals space
        const float* nw = (c0 < 2048) ? qnw : knw;
        float r1 = rrms[c0 >> 7];
        const float* ct = cost + t * 64;
        const float* st = sint + t * 64;
        __align__(16) bf16 outv[8];
        #pragma unroll
        for (int j = 0; j < 8; ++j) {
            int jj = j0 + j;
            float xn = vals[hb + jj] * r1 * nw[jj];
            int pj = (jj < 64) ? jj + 64 : jj - 64;
            float xp = vals[hb + pj] * r1 * nw[pj];
            float rot = (jj < 64) ? -xp : xp;
            int fi = jj & 63;
            outv[j] = (bf16)(xn * ct[fi] + rot * st[fi]);
        }
        bf16* dst = (c0 < 2048)
            ? qf + ((((size_t)b * H_  + head) * S_ + t) << 7) + j0
            : kf + ((((size_t)b * KVH_ + head) * S_ + t) << 7) + j0;
        *(float4*)dst = *(float4*)outv;
    } else {             // v: conv only
        int ch = c0 - 3072;
        int head = ch >> 7, j0 = ch & 127;
        __align__(16) bf16 outv[8];
        #pragma unroll
        for (int j = 0; j < 8; ++j) outv[j] = (bf16)acc[j];
        bf16* dst = vf + ((((size_t)b * KVH_ + head) * S_ + t) << 7) + j0;
        *(float4*)dst = *(float4*)outv;
    }
}

// ---------------------------------------------------------------- V transpose: [bk][S][128] -> [bk][128][S]
__global__ __launch_bounds__(256) void transpose_v(const bf16* __restrict__ vf,
                                                   bf16* __restrict__ vfT) {
    __shared__ __align__(16) bf16 tile[64][72];
    int bk = blockIdx.z;
    int t0 = blockIdx.x * 64;
    int d0 = blockIdx.y * 64;
    int tid = threadIdx.x;
    const bf16* src = vf + ((size_t)bk * S_ << 7);
    {
        int r = tid >> 3, cs = (tid & 7) << 3;
        #pragma unroll
        for (int p = 0; p < 2; ++p)
            *(float4*)(&tile[r + p * 32][cs]) =
                *(const float4*)(src + (size_t)(t0 + r + p * 32) * 128 + d0 + cs);
    }
    __syncthreads();
    {
        int dr = tid >> 3, ts = (tid & 7) << 3;
        #pragma unroll
        for (int p = 0; p < 2; ++p) {
            __align__(16) bf16 outv[8];
            #pragma unroll
            for (int j = 0; j < 8; ++j) outv[j] = tile[ts + j][dr + p * 32];
            *(float4*)(vfT + ((size_t)bk * 128 + d0 + dr + p * 32) * S_ + t0 + ts) = *(float4*)outv;
        }
    }
}

// ---------------------------------------------------------------- flash attention (causal, GQA groups=2)
// Barrier-free: 4 independent waves per block; K/V B-fragments read straight
// from global (L2-resident), LDS only for the per-wave P C->A roundtrip.
// qf[B][H][S][128], kf[B][KVH][S][128], vfT[B][KVH][128][S] -> attn[B][S][H*128]
__global__ __launch_bounds__(256) void flash_attn(const bf16* __restrict__ qf,
                                                  const bf16* __restrict__ kf,
                                                  const bf16* __restrict__ vfT,
                                                  bf16* __restrict__ attn) {
    __shared__ __align__(16) bf16 Pls[4][16][72];  // per-wave P, +8 pad
    int lid  = blockIdx.x;                         // 0..1023
    int pair = lid & 15;                           // (b*8+kvh) -> stable XCD via lid%8
    int b    = pair >> 3, kvh = pair & 7;
    int inner = lid >> 4;                          // 0..63
    int qt   = 31 - (inner >> 1);                  // longest q-tiles first
    int h    = kvh * 2 + (inner & 1);
    int tid = threadIdx.x, wave = tid >> 6, lane = tid & 63;
    int quad = lane >> 4, l16 = lane & 15;
    int qrow0 = (qt << 6) + (wave << 4);           // wave's 16 q rows

    const bf16* kbase = kf  + (((size_t)b * KVH_ + kvh) * S_ << 7);
    const bf16* vbase = vfT + (((size_t)b * KVH_ + kvh) << 7) * S_;

    bf16x8 aq[4];   // Q A-frags over d (4 * 32)
    {
        const bf16* qr = qf + ((((size_t)b * H_ + h) * S_ + qrow0 + l16) << 7) + (quad << 3);
        #pragma unroll
        for (int ks = 0; ks < 4; ++ks) aq[ks] = *(const bf16x8*)(qr + ks * 32);
    }
    floatx4 o[8] = {};
    float m_i[4] = {-1e30f, -1e30f, -1e30f, -1e30f};
    float l_i[4] = {0.f, 0.f, 0.f, 0.f};
    // softmax in exp2 domain: fold scale * log2(e) into the score scaling
    const float scl2 = 0.08838834764831845f * 1.4426950408889634f;

    int ktiles = qt + 1;
    for (int kt = 0; kt < ktiles; ++kt) {
        int kb = kt << 6;
        // S = Q K^T ; K B-frag straight from global: B[n=key][k=d]
        floatx4 sc[4] = {};
        #pragma unroll
        for (int nt = 0; nt < 4; ++nt) {
            const bf16* kr = kbase + ((size_t)(kb + nt * 16 + l16) << 7) + (quad << 3);
            #pragma unroll
            for (int ks = 0; ks < 4; ++ks) {
                bf16x8 kb8 = *(const bf16x8*)(kr + ks * 32);
                sc[nt] = __builtin_amdgcn_mfma_f32_16x16x32_bf16(aq[ks], kb8, sc[nt], 0, 0, 0);
            }
        }
        // scale (log2 domain) + causal mask
        int qr0 = qrow0 + (quad << 2);
        #pragma unroll
        for (int nt = 0; nt < 4; ++nt) {
            int key = kb + nt * 16 + l16;
            #pragma unroll
            for (int r = 0; r < 4; ++r) {
                float s = sc[nt][r] * scl2;
                sc[nt][r] = (key <= qr0 + r) ? s : -1e30f;
            }
        }
        // online softmax (per lane: 4 rows; row spread over 16 l16-lanes)
        #pragma unroll
        for (int r = 0; r < 4; ++r) {
            float mx = fmaxf(fmaxf(sc[0][r], sc[1][r]), fmaxf(sc[2][r], sc[3][r]));
            mx = fmaxf(mx, __shfl_xor(mx, 1)); mx = fmaxf(mx, __shfl_xor(mx, 2));
            mx = fmaxf(mx, __shfl_xor(mx, 4)); mx = fmaxf(mx, __shfl_xor(mx, 8));
            float mnew = fmaxf(m_i[r], mx);
            float alpha = exp2f(m_i[r] - mnew);
            m_i[r] = mnew;
            float sum = 0.f;
            #pragma unroll
            for (int nt = 0; nt < 4; ++nt) {
                float pv = exp2f(sc[nt][r] - mnew);
                sc[nt][r] = pv;
                sum += pv;
            }
            sum += __shfl_xor(sum, 1); sum += __shfl_xor(sum, 2);
            sum += __shfl_xor(sum, 4); sum += __shfl_xor(sum, 8);
            l_i[r] = l_i[r] * alpha + sum;
            #pragma unroll
            for (int dnt = 0; dnt < 8; ++dnt) o[dnt][r] *= alpha;
            #pragma unroll
            for (int nt = 0; nt < 4; ++nt)
                Pls[wave][(quad << 2) + r][nt * 16 + l16] = (bf16)sc[nt][r];
        }
        // O += P V ; V B-frag straight from global vfT: B[n=d][k=key]
        // (same-wave LDS write->read: compiler inserts lgkmcnt wait, no barrier)
        #pragma unroll
        for (int ks = 0; ks < 2; ++ks) {
            bf16x8 pa = *(const bf16x8*)(&Pls[wave][l16][ks * 32 + (quad << 3)]);
            #pragma unroll
            for (int dnt = 0; dnt < 8; ++dnt) {
                bf16x8 vb = *(const bf16x8*)(vbase + (size_t)(dnt * 16 + l16) * S_
                                             + kb + ks * 32 + (quad << 3));
                o[dnt] = __builtin_amdgcn_mfma_f32_16x16x32_bf16(pa, vb, o[dnt], 0, 0, 0);
            }
        }
    }
    // epilogue: attn[b][q][h*128 + d] = o / l
    #pragma unroll
    for (int dnt = 0; dnt < 8; ++dnt) {
        #pragma unroll
        for (int r = 0; r < 4; ++r) {
            size_t row = (size_t)b * S_ + qrow0 + (quad << 2) + r;
            attn[row * D_ + h * DH_ + dnt * 16 + l16] = (bf16)(o[dnt][r] / l_i[r]);
        }
    }
}

// ---------------------------------------------------------------- launch
extern "C" void kernel_launch(void* const* d_in, const int* in_sizes, int n_in,
                              void* d_out, int out_size, void* d_ws, size_t ws_size,
                              hipStream_t stream) {
    // Inputs are float32 (per reference); output is float32.
    const float* hidden = (const float*)d_in[0];
    const float* Wq  = (const float*)d_in[1];
    const float* Wk  = (const float*)d_in[2];
    const float* Wv  = (const float*)d_in[3];
    const float* Wo  = (const float*)d_in[4];
    const float* cqw = (const float*)d_in[5];
    const float* ckw = (const float*)d_in[6];
    const float* cvw = (const float*)d_in[7];
    const float* qnw = (const float*)d_in[8];
    const float* knw = (const float*)d_in[9];

    char* p = (char*)d_ws;
    auto alloc = [&](size_t bytes) { char* r = p; p += (bytes + 255) & ~(size_t)255; return r; };
    bf16*  X    = (bf16*)alloc((size_t)M_ * D_ * 2);
    bf16*  Wcat = (bf16*)alloc((size_t)NQKV_ * D_ * 2);
    bf16*  Wob  = (bf16*)alloc((size_t)D_ * D_ * 2);
    bf16*  QKV  = (bf16*)alloc((size_t)M_ * NQKV_ * 2);
    bf16*  qfb  = (bf16*)alloc((size_t)B_ * H_ * S_ * DH_ * 2);
    bf16*  kfb  = (bf16*)alloc((size_t)B_ * KVH_ * S_ * DH_ * 2);
    bf16*  vfb  = (bf16*)alloc((size_t)B_ * KVH_ * S_ * DH_ * 2);
    bf16*  vfT  = (bf16*)alloc((size_t)B_ * KVH_ * S_ * DH_ * 2);
    float* cost = (float*)alloc((size_t)S_ * 64 * 4);
    float* sint = (float*)alloc((size_t)S_ * 64 * 4);
    bf16*  attnb = QKV;   // QKV is dead after canon_kernel; reuse as attention output

    cast_kernel<<<M_ * D_ / 4 / 256, 256, 0, stream>>>(hidden, X, M_ * D_);
    cast_kernel<<<D_ * D_ / 4 / 256, 256, 0, stream>>>(Wq, Wcat, D_ * D_);
    cast_kernel<<<1024 * 2048 / 4 / 256, 256, 0, stream>>>(Wk, Wcat + (size_t)2048 * 2048, 1024 * 2048);
    cast_kernel<<<1024 * 2048 / 4 / 256, 256, 0, stream>>>(Wv, Wcat + (size_t)3072 * 2048, 1024 * 2048);
    cast_kernel<<<D_ * D_ / 4 / 256, 256, 0, stream>>>(Wo, Wob, D_ * D_);
    rope_table<<<S_ * 64 / 256, 256, 0, stream>>>(cost, sint);

    gemm_bt<bf16><<<dim3(NQKV_ / BN, M_ / BM), 256, 0, stream>>>(X, Wcat, QKV, M_, NQKV_, D_);
    canon_kernel<<<M_, 512, 0, stream>>>(QKV, cqw, ckw, cvw, qnw, knw, cost, sint, qfb, kfb, vfb);
    transpose_v<<<dim3(S_ / 64, DH_ / 64, B_ * KVH_), 256, 0, stream>>>(vfb, vfT);
    flash_attn<<<1024, 256, 0, stream>>>(qfb, kfb, vfT, attnb);
    gemm_bt<float><<<dim3(D_ / BN, M_ / BM), 256, 0, stream>>>(attnb, Wob, (float*)d_out, M_, D_, D_);
}